// Round 3
// baseline (1858.536 us; speedup 1.0000x reference)
//
#include <hip/hip_runtime.h>
#include <hip/hip_bf16.h>
#include <math.h>
#include <stdint.h>

#define N_ATOMS 512
#define NF 64
#define NB 8
#define NBINS 64
#define NSEG 511   // segment nodes 0..510; valid pairs i<j, j>=i+2

__device__ __forceinline__ float dot3(float ax, float ay, float az,
                                      float bx, float by, float bz) {
    return fmaf(ax, bx, fmaf(ay, by, az * bz));
}

__device__ __forceinline__ uint16_t bf16_bits(float f) {
    __hip_bfloat16 h = __float2bfloat16(f);
    union { __hip_bfloat16 h; uint16_t u; } cv;
    cv.h = h;
    return cv.u;
}

// Full per-edge pipeline: writhe -> rbf -> MLP -> m[64]. lane = edge.
__device__ __forceinline__ void compute_m(
        const float* __restrict__ pb,   // xyz + batch*N_ATOMS*3
        int i, int j,
        const float* __restrict__ W1, const float* __restrict__ b1,
        const float* __restrict__ W2, const float* __restrict__ b2,
        float* __restrict__ mout /*[64]*/) {
    float p0x = pb[3*i+0], p0y = pb[3*i+1], p0z = pb[3*i+2];
    float p1x = pb[3*i+3], p1y = pb[3*i+4], p1z = pb[3*i+5];
    float p2x = pb[3*j+0], p2y = pb[3*j+1], p2z = pb[3*j+2];
    float p3x = pb[3*j+3], p3y = pb[3*j+4], p3z = pb[3*j+5];

    float d0x = p2x-p0x, d0y = p2y-p0y, d0z = p2z-p0z;
    float d1x = p3x-p0x, d1y = p3y-p0y, d1z = p3z-p0z;
    float d2x = p2x-p1x, d2y = p2y-p1y, d2z = p2z-p1z;
    float d3x = p3x-p1x, d3y = p3y-p1y, d3z = p3z-p1z;
    {
        float n0 = rsqrtf(dot3(d0x,d0y,d0z,d0x,d0y,d0z)); d0x*=n0; d0y*=n0; d0z*=n0;
        float n1 = rsqrtf(dot3(d1x,d1y,d1z,d1x,d1y,d1z)); d1x*=n1; d1y*=n1; d1z*=n1;
        float n2 = rsqrtf(dot3(d2x,d2y,d2z,d2x,d2y,d2z)); d2x*=n2; d2y*=n2; d2z*=n2;
        float n3 = rsqrtf(dot3(d3x,d3y,d3z,d3x,d3y,d3z)); d3x*=n3; d3y*=n3; d3z*=n3;
    }
    // crosses c0=n(d0xd1) c1=n(d1xd3) c3=n(d2xd0); dots (c0.c1),(c1.c3),(c2.c2)=1,(c3.c0)
    float c0x = d0y*d1z - d0z*d1y, c0y = d0z*d1x - d0x*d1z, c0z = d0x*d1y - d0y*d1x;
    float c1x = d1y*d3z - d1z*d3y, c1y = d1z*d3x - d1x*d3z, c1z = d1x*d3y - d1y*d3x;
    float c3x = d2y*d0z - d2z*d0y, c3y = d2z*d0x - d2x*d0z, c3z = d2x*d0y - d2y*d0x;
    {
        float n0 = rsqrtf(dot3(c0x,c0y,c0z,c0x,c0y,c0z)); c0x*=n0; c0y*=n0; c0z*=n0;
        float n1 = rsqrtf(dot3(c1x,c1y,c1z,c1x,c1y,c1z)); c1x*=n1; c1y*=n1; c1z*=n1;
        float n3 = rsqrtf(dot3(c3x,c3y,c3z,c3x,c3y,c3z)); c3x*=n3; c3y*=n3; c3z*=n3;
    }
    float t0 = fminf(fmaxf(dot3(c0x,c0y,c0z, c1x,c1y,c1z), -1.f), 1.f);
    float t1 = fminf(fmaxf(dot3(c1x,c1y,c1z, c3x,c3y,c3z), -1.f), 1.f);
    float t3 = fminf(fmaxf(dot3(c3x,c3y,c3z, c0x,c0y,c0z), -1.f), 1.f);
    float omega = asinf(t0) + asinf(t1) + asinf(t3) + 1.5707963267948966f;
    float ex = p3x-p2x, ey = p3y-p2y, ez = p3z-p2z;
    float fx = p1x-p0x, fy = p1y-p0y, fz = p1z-p0z;
    float gx = ey*fz - ez*fy, gy = ez*fx - ex*fz, gz = ex*fy - ey*fx;
    float sgd = dot3(gx,gy,gz, d0x,d0y,d0z);
    float sgn = (sgd > 0.f) ? 1.f : ((sgd < 0.f) ? -1.f : 0.f);
    float wr = omega * sgn * 0.15915494309189535f;

    // RBF (reused buffer also holds m at the end)
    float acc_[NBINS];
    {
        float tt = (wr + 1.0f) * 31.5f;
        #pragma unroll
        for (int k = 0; k < NBINS; ++k) {
            float d = tt - (float)k;
            acc_[k] = __expf(-d * d) * 0.8928571428571429f;
        }
    }
    float h_[NF];
    #pragma unroll
    for (int f = 0; f < NF; ++f) h_[f] = b1[f];
    #pragma unroll
    for (int k = 0; k < NBINS; ++k) {
        float r = acc_[k];
        #pragma unroll
        for (int f = 0; f < NF; ++f) h_[f] = fmaf(r, W1[k * NF + f], h_[f]);
    }
    #pragma unroll
    for (int f = 0; f < NF; ++f) h_[f] = fmaxf(h_[f], 0.01f * h_[f]);

    #pragma unroll
    for (int f = 0; f < NF; ++f) acc_[f] = b2[f];
    #pragma unroll
    for (int k = 0; k < NF; ++k) {
        float hk = h_[k];
        #pragma unroll
        for (int f = 0; f < NF; ++f) acc_[f] = fmaf(hk, W2[k * NF + f], acc_[f]);
    }
    #pragma unroll
    for (int f = 0; f < NF; ++f) mout[f] = acc_[f];
}

// ---------------- main path: two-pass, atomic-free ----------------

// Pass 1: per (b, edge) compute m[64], store bf16 row to workspace.
__launch_bounds__(256, 2)
__global__ void pass1_msg_kernel(
        const float* __restrict__ xyz, const int* __restrict__ seg,
        const float* __restrict__ W1, const float* __restrict__ b1,
        const float* __restrict__ W2, const float* __restrict__ b2,
        uint16_t* __restrict__ mws, int P, int n_tiles) {
    const int lane = threadIdx.x & 63;
    const int wave_g = (blockIdx.x * blockDim.x + threadIdx.x) >> 6;
    const int b = wave_g / n_tiles;
    const int tile = wave_g - b * n_tiles;
    const int bc = (b < NB) ? b : 0;
    const int e = tile * 64 + lane;
    const bool valid = (b < NB) && (e < P);

    int4 sv = valid ? ((const int4*)seg)[e] : make_int4(0, 1, 2, 3);
    float m[NF];
    compute_m(xyz + bc * (N_ATOMS * 3), sv.x, sv.z, W1, b1, W2, b2, m);

    if (valid) {
        uint16_t* row = mws + (size_t)(b * P + e) * NF;   // 128-B aligned rows
        #pragma unroll
        for (int q = 0; q < 8; ++q) {
            uint4 v;
            v.x = (uint32_t)bf16_bits(m[8*q+0]) | ((uint32_t)bf16_bits(m[8*q+1]) << 16);
            v.y = (uint32_t)bf16_bits(m[8*q+2]) | ((uint32_t)bf16_bits(m[8*q+3]) << 16);
            v.z = (uint32_t)bf16_bits(m[8*q+4]) | ((uint32_t)bf16_bits(m[8*q+5]) << 16);
            v.w = (uint32_t)bf16_bits(m[8*q+6]) | ((uint32_t)bf16_bits(m[8*q+7]) << 16);
            ((uint4*)row)[q] = v;
        }
    }
}

// Pass 2: one wave per (b, dst atom), lane = feature. Gather over all sources
// using the analytic pair index: edges are (i<j, j>=i+2), off(i)=509i-i(i-1)/2,
// e(i,j) = off(i) + j - i - 2. out = x + agg. No atomics.
__launch_bounds__(256, 4)
__global__ void pass2_agg_kernel(
        const float* __restrict__ x, const uint16_t* __restrict__ mws,
        float* __restrict__ out, int P) {
    const int lane = threadIdx.x & 63;
    const int gw = blockIdx.x * 4 + (threadIdx.x >> 6);  // 0 .. 4095
    const int b = gw >> 9;
    const int dst = gw & (N_ATOMS - 1);
    const float* xb = x + (size_t)b * (N_ATOMS * NF);
    const uint16_t* mb = mws + (size_t)b * P * NF;

    float acc = 0.0f;
    if (dst < NSEG) {
        // sources below: i = src, j = dst
        #pragma unroll 4
        for (int src = 0; src <= dst - 2; ++src) {
            int e = 509 * src - ((src * (src - 1)) >> 1) + (dst - src - 2);
            float mv = __uint_as_float((uint32_t)mb[(size_t)e * NF + lane] << 16);
            acc = fmaf(mv, xb[src * NF + lane], acc);
        }
        // sources above: i = dst, j = src  (consecutive e — streaming)
        const int off_d = 509 * dst - ((dst * (dst - 1)) >> 1);
        #pragma unroll 4
        for (int src = dst + 2; src < NSEG; ++src) {
            int e = off_d + (src - dst - 2);
            float mv = __uint_as_float((uint32_t)mb[(size_t)e * NF + lane] << 16);
            acc = fmaf(mv, xb[src * NF + lane], acc);
        }
    }
    out[(size_t)b * (N_ATOMS * NF) + dst * NF + lane] = xb[dst * NF + lane] + acc;
}

// ---------------- fallback path (ws too small): R2 atomic kernel ----------------

__global__ void init_out_kernel(const float* __restrict__ x, float* __restrict__ out, int n) {
    int idx = blockIdx.x * blockDim.x + threadIdx.x;
    if (idx < n) out[idx] = x[idx];
}

__launch_bounds__(256, 2)
__global__ void writhe_msg_atomic_kernel(
        const float* __restrict__ x, const float* __restrict__ xyz,
        const int* __restrict__ seg,
        const float* __restrict__ W1, const float* __restrict__ b1,
        const float* __restrict__ W2, const float* __restrict__ b2,
        float* __restrict__ out, int P, int n_tiles) {
    __shared__ __hip_bfloat16 lds_m[4][64 * 65];
    __shared__ int lds_i[4][64];
    __shared__ int lds_j[4][64];

    const int widx = threadIdx.x >> 6;
    const int lane = threadIdx.x & 63;
    const int wave_g = blockIdx.x * 4 + widx;
    const int b = wave_g / n_tiles;
    const int tile = wave_g - b * n_tiles;
    const int bc = (b < NB) ? b : 0;
    const int e = tile * 64 + lane;
    const bool valid = (b < NB) && (e < P);

    int4 sv = valid ? ((const int4*)seg)[e] : make_int4(0, 1, 2, 3);
    const int i = sv.x;
    const int j = sv.z;

    float m[NF];
    compute_m(xyz + bc * (N_ATOMS * 3), i, j, W1, b1, W2, b2, m);

    const float scale = valid ? 1.0f : 0.0f;
    #pragma unroll
    for (int f = 0; f < NF; ++f)
        lds_m[widx][lane * 65 + f] = __float2bfloat16(m[f] * scale);
    lds_i[widx][lane] = i;
    lds_j[widx][lane] = j;
    __syncthreads();

    const float* xb = x + bc * (N_ATOMS * NF);
    float* ob = out + bc * (N_ATOMS * NF);
    int cur_i = lds_i[widx][0];
    float acc_i = 0.0f;
    for (int ee = 0; ee < 64; ++ee) {
        int ie = lds_i[widx][ee];
        int je = lds_j[widx][ee];
        float mv = __bfloat162float(lds_m[widx][ee * 65 + lane]);
        float xi = xb[ie * NF + lane];
        float xj = xb[je * NF + lane];
        atomicAdd(&ob[je * NF + lane], mv * xi);
        if (ie != cur_i) {
            atomicAdd(&ob[cur_i * NF + lane], acc_i);
            acc_i = 0.0f;
            cur_i = ie;
        }
        acc_i = fmaf(mv, xj, acc_i);
    }
    atomicAdd(&ob[cur_i * NF + lane], acc_i);
}

extern "C" void kernel_launch(void* const* d_in, const int* in_sizes, int n_in,
                              void* d_out, int out_size, void* d_ws, size_t ws_size,
                              hipStream_t stream) {
    const float* x   = (const float*)d_in[0];
    const float* xyz = (const float*)d_in[1];
    const int*   seg = (const int*)d_in[2];
    const float* W1  = (const float*)d_in[3];
    const float* b1  = (const float*)d_in[4];
    const float* W2  = (const float*)d_in[5];
    const float* b2  = (const float*)d_in[6];
    float* out = (float*)d_out;

    const int P = in_sizes[2] / 4;              // 129795 edges
    const int n_tiles = (P + 63) / 64;
    const size_t need_ws = (size_t)NB * P * NF * sizeof(uint16_t);  // ~127 MiB

    if (ws_size >= need_ws) {
        // two-pass atomic-free path
        uint16_t* mws = (uint16_t*)d_ws;
        const int total_waves = NB * n_tiles;
        const int blocks1 = (total_waves + 3) / 4;
        hipLaunchKernelGGL(pass1_msg_kernel, dim3(blocks1), dim3(256), 0, stream,
                           xyz, seg, W1, b1, W2, b2, mws, P, n_tiles);
        const int blocks2 = (NB * N_ATOMS) / 4;  // 1024
        hipLaunchKernelGGL(pass2_agg_kernel, dim3(blocks2), dim3(256), 0, stream,
                           x, mws, out, P);
    } else {
        // fallback: proven R2 atomic path
        const int n = out_size;
        hipLaunchKernelGGL(init_out_kernel, dim3((n + 255) / 256), dim3(256), 0, stream,
                           x, out, n);
        const int total_waves = NB * n_tiles;
        const int blocks = (total_waves + 3) / 4;
        hipLaunchKernelGGL(writhe_msg_atomic_kernel, dim3(blocks), dim3(256), 0, stream,
                           x, xyz, seg, W1, b1, W2, b2, out, P, n_tiles);
    }
}

// Round 6
// 211.913 us; speedup vs baseline: 8.7703x; 8.7703x over previous
//
#include <hip/hip_runtime.h>
#include <hip/hip_bf16.h>
#include <math.h>
#include <stdint.h>

#define N_ATOMS 512
#define NF 64
#define NB 8
#define NBINS 64
#define NSEG 511   // segment nodes 0..510; valid pairs i<j, j>=i+2
#define NT 4096    // m(wr) lookup-table grid points over wr in [-1,1]

__device__ __forceinline__ float dot3(float ax, float ay, float az,
                                      float bx, float by, float bz) {
    return fmaf(ax, bx, fmaf(ay, by, az * bz));
}

__device__ __forceinline__ uint16_t bf16_bits(float f) {
    union { __hip_bfloat16 h; uint16_t u; } cv;
    cv.h = __float2bfloat16(f);
    return cv.u;
}

// writhe scalar for edge (i,j) — verified vs reference (R2/R3 absmax 0.0625)
__device__ __forceinline__ float compute_wr(const float* __restrict__ pb, int i, int j) {
    float p0x = pb[3*i+0], p0y = pb[3*i+1], p0z = pb[3*i+2];
    float p1x = pb[3*i+3], p1y = pb[3*i+4], p1z = pb[3*i+5];
    float p2x = pb[3*j+0], p2y = pb[3*j+1], p2z = pb[3*j+2];
    float p3x = pb[3*j+3], p3y = pb[3*j+4], p3z = pb[3*j+5];

    float d0x = p2x-p0x, d0y = p2y-p0y, d0z = p2z-p0z;
    float d1x = p3x-p0x, d1y = p3y-p0y, d1z = p3z-p0z;
    float d2x = p2x-p1x, d2y = p2y-p1y, d2z = p2z-p1z;
    float d3x = p3x-p1x, d3y = p3y-p1y, d3z = p3z-p1z;
    {
        float n0 = rsqrtf(dot3(d0x,d0y,d0z,d0x,d0y,d0z)); d0x*=n0; d0y*=n0; d0z*=n0;
        float n1 = rsqrtf(dot3(d1x,d1y,d1z,d1x,d1y,d1z)); d1x*=n1; d1y*=n1; d1z*=n1;
        float n2 = rsqrtf(dot3(d2x,d2y,d2z,d2x,d2y,d2z)); d2x*=n2; d2y*=n2; d2z*=n2;
        float n3 = rsqrtf(dot3(d3x,d3y,d3z,d3x,d3y,d3z)); d3x*=n3; d3y*=n3; d3z*=n3;
    }
    float c0x = d0y*d1z - d0z*d1y, c0y = d0z*d1x - d0x*d1z, c0z = d0x*d1y - d0y*d1x;
    float c1x = d1y*d3z - d1z*d3y, c1y = d1z*d3x - d1x*d3z, c1z = d1x*d3y - d1y*d3x;
    float c3x = d2y*d0z - d2z*d0y, c3y = d2z*d0x - d2x*d0z, c3z = d2x*d0y - d2y*d0x;
    {
        float n0 = rsqrtf(dot3(c0x,c0y,c0z,c0x,c0y,c0z)); c0x*=n0; c0y*=n0; c0z*=n0;
        float n1 = rsqrtf(dot3(c1x,c1y,c1z,c1x,c1y,c1z)); c1x*=n1; c1y*=n1; c1z*=n1;
        float n3 = rsqrtf(dot3(c3x,c3y,c3z,c3x,c3y,c3z)); c3x*=n3; c3y*=n3; c3z*=n3;
    }
    float t0 = fminf(fmaxf(dot3(c0x,c0y,c0z, c1x,c1y,c1z), -1.f), 1.f);
    float t1 = fminf(fmaxf(dot3(c1x,c1y,c1z, c3x,c3y,c3z), -1.f), 1.f);
    float t3 = fminf(fmaxf(dot3(c3x,c3y,c3z, c0x,c0y,c0z), -1.f), 1.f);
    float omega = asinf(t0) + asinf(t1) + asinf(t3) + 1.5707963267948966f;
    float ex = p3x-p2x, ey = p3y-p2y, ez = p3z-p2z;
    float fx = p1x-p0x, fy = p1y-p0y, fz = p1z-p0z;
    float gx = ey*fz - ez*fy, gy = ez*fx - ex*fz, gz = ex*fy - ey*fx;
    float sgd = dot3(gx,gy,gz, d0x,d0y,d0z);
    float sgn = (sgd > 0.f) ? 1.f : ((sgd < 0.f) ? -1.f : 0.f);
    return omega * sgn * 0.15915494309189535f;
}

// ---------------- kernel 0: build m(wr) lookup table ----------------------------
// Grid wr_g = -1 + 2g/(NT-1). Thread (g, fc): computes full h[64] (R2-proven fp32
// MLP), then 8 output features m[fc*8 .. fc*8+7]. tab stored in d_out (1 MB),
// consumed by pass1, then fully overwritten by pass2.
__global__ void build_tab(const float* __restrict__ W1, const float* __restrict__ b1,
                          const float* __restrict__ W2, const float* __restrict__ b2,
                          float* __restrict__ tab) {
    int tid = blockIdx.x * blockDim.x + threadIdx.x;   // 0 .. 32767
    int g  = tid >> 3;
    int fc = (tid & 7) * 8;
    if (g >= NT) return;
    float wr = -1.0f + (2.0f / (float)(NT - 1)) * (float)g;
    float tt = (wr + 1.0f) * 31.5f;

    float rbf[NBINS];
    #pragma unroll
    for (int k = 0; k < NBINS; ++k) {
        float d = tt - (float)k;
        rbf[k] = __expf(-d * d) * 0.8928571428571429f;
    }
    float h_[NF];
    #pragma unroll
    for (int f = 0; f < NF; ++f) h_[f] = b1[f];
    #pragma unroll 8
    for (int k = 0; k < NBINS; ++k) {
        float r = rbf[k];
        #pragma unroll
        for (int f = 0; f < NF; ++f) h_[f] = fmaf(r, W1[k * NF + f], h_[f]);
    }
    #pragma unroll
    for (int f = 0; f < NF; ++f) h_[f] = fmaxf(h_[f], 0.01f * h_[f]);

    float m[8];
    #pragma unroll
    for (int f = 0; f < 8; ++f) m[f] = b2[fc + f];
    #pragma unroll 8
    for (int k = 0; k < NF; ++k) {
        float hk = h_[k];
        #pragma unroll
        for (int f = 0; f < 8; ++f) m[f] = fmaf(hk, W2[k * NF + fc + f], m[f]);
    }
    #pragma unroll
    for (int f = 0; f < 8; ++f) tab[g * NF + fc + f] = m[f];
}

// ---------------- pass 1: geometry + table lerp -> coalesced bf16 m rows --------
__launch_bounds__(256, 2)
__global__ void pass1_tab(
        const float* __restrict__ xyz, const int* __restrict__ seg,
        const float* __restrict__ tab, uint16_t* __restrict__ mws,
        int P, int n_tiles) {
    __shared__ float lds_wr[4][64];

    const int widx = threadIdx.x >> 6;
    const int lane = threadIdx.x & 63;
    const int wave_g = blockIdx.x * 4 + widx;
    const int b = wave_g / n_tiles;        // grid sized exactly: b < NB always
    const int t = wave_g - b * n_tiles;
    const int e = t * 64 + lane;
    const bool valid = (e < P);

    int4 sv = valid ? ((const int4*)seg)[e] : make_int4(0, 1, 2, 3);
    float wr = compute_wr(xyz + b * (N_ATOMS * 3), sv.x, sv.z);
    lds_wr[widx][lane] = valid ? wr : 0.0f;
    __syncthreads();

    // lane = feature; per edge: two coalesced 256B table reads + lerp + 128B store
    uint16_t* rowbase = mws + (size_t)(b * P + t * 64) * NF;
    const int nval = (P - t * 64 < 64) ? (P - t * 64) : 64;
    #pragma unroll 4
    for (int ee = 0; ee < nval; ++ee) {
        float w  = lds_wr[widx][ee];
        float tf = (w + 1.0f) * ((float)(NT - 1) * 0.5f);   // index in [0, 4095]
        tf = fminf(fmaxf(tf, 0.0f), (float)(NT - 1));
        int   t0 = (int)tf;
        t0 = (t0 > NT - 2) ? (NT - 2) : t0;
        float al = tf - (float)t0;
        float m0 = tab[t0 * NF + lane];
        float m1 = tab[t0 * NF + NF + lane];
        float mv = fmaf(al, m1 - m0, m0);
        rowbase[(size_t)ee * NF + lane] = bf16_bits(mv);
    }
}

// ---------------- pass 2: gather-aggregate (unchanged — validated in R3) ----------
__launch_bounds__(256, 4)
__global__ void pass2_agg_kernel(
        const float* __restrict__ x, const uint16_t* __restrict__ mws,
        float* __restrict__ out, int P) {
    const int lane = threadIdx.x & 63;
    const int gw = blockIdx.x * 4 + (threadIdx.x >> 6);  // 0 .. 4095
    const int b = gw >> 9;
    const int dst = gw & (N_ATOMS - 1);
    const float* xb = x + (size_t)b * (N_ATOMS * NF);
    const uint16_t* mb = mws + (size_t)b * P * NF;

    float acc = 0.0f;
    if (dst < NSEG) {
        #pragma unroll 4
        for (int src = 0; src <= dst - 2; ++src) {
            int e = 509 * src - ((src * (src - 1)) >> 1) + (dst - src - 2);
            float mv = __uint_as_float((uint32_t)mb[(size_t)e * NF + lane] << 16);
            acc = fmaf(mv, xb[src * NF + lane], acc);
        }
        const int off_d = 509 * dst - ((dst * (dst - 1)) >> 1);
        #pragma unroll 4
        for (int src = dst + 2; src < NSEG; ++src) {
            int e = off_d + (src - dst - 2);
            float mv = __uint_as_float((uint32_t)mb[(size_t)e * NF + lane] << 16);
            acc = fmaf(mv, xb[src * NF + lane], acc);
        }
    }
    out[(size_t)b * (N_ATOMS * NF) + dst * NF + lane] = xb[dst * NF + lane] + acc;
}

// ---------------- fallback path (ws too small): R2 atomic kernel (proven) --------

__global__ void init_out_kernel(const float* __restrict__ x, float* __restrict__ out, int n) {
    int idx = blockIdx.x * blockDim.x + threadIdx.x;
    if (idx < n) out[idx] = x[idx];
}

__device__ __forceinline__ void compute_m(
        const float* __restrict__ pb, int i, int j,
        const float* __restrict__ W1, const float* __restrict__ b1,
        const float* __restrict__ W2, const float* __restrict__ b2,
        float* __restrict__ mout) {
    float wr = compute_wr(pb, i, j);
    float acc_[NBINS];
    {
        float tt = (wr + 1.0f) * 31.5f;
        #pragma unroll
        for (int k = 0; k < NBINS; ++k) {
            float d = tt - (float)k;
            acc_[k] = __expf(-d * d) * 0.8928571428571429f;
        }
    }
    float h_[NF];
    #pragma unroll
    for (int f = 0; f < NF; ++f) h_[f] = b1[f];
    #pragma unroll
    for (int k = 0; k < NBINS; ++k) {
        float r = acc_[k];
        #pragma unroll
        for (int f = 0; f < NF; ++f) h_[f] = fmaf(r, W1[k * NF + f], h_[f]);
    }
    #pragma unroll
    for (int f = 0; f < NF; ++f) h_[f] = fmaxf(h_[f], 0.01f * h_[f]);
    #pragma unroll
    for (int f = 0; f < NF; ++f) acc_[f] = b2[f];
    #pragma unroll
    for (int k = 0; k < NF; ++k) {
        float hk = h_[k];
        #pragma unroll
        for (int f = 0; f < NF; ++f) acc_[f] = fmaf(hk, W2[k * NF + f], acc_[f]);
    }
    #pragma unroll
    for (int f = 0; f < NF; ++f) mout[f] = acc_[f];
}

__launch_bounds__(256, 2)
__global__ void writhe_msg_atomic_kernel(
        const float* __restrict__ x, const float* __restrict__ xyz,
        const int* __restrict__ seg,
        const float* __restrict__ W1, const float* __restrict__ b1,
        const float* __restrict__ W2, const float* __restrict__ b2,
        float* __restrict__ out, int P, int n_tiles) {
    __shared__ __hip_bfloat16 lds_m[4][64 * 65];
    __shared__ int lds_i[4][64];
    __shared__ int lds_j[4][64];

    const int widx = threadIdx.x >> 6;
    const int lane = threadIdx.x & 63;
    const int wave_g = blockIdx.x * 4 + widx;
    const int b = wave_g / n_tiles;
    const int tile = wave_g - b * n_tiles;
    const int bc = (b < NB) ? b : 0;
    const int e = tile * 64 + lane;
    const bool valid = (b < NB) && (e < P);

    int4 sv = valid ? ((const int4*)seg)[e] : make_int4(0, 1, 2, 3);
    const int i = sv.x;
    const int j = sv.z;

    float m[NF];
    compute_m(xyz + bc * (N_ATOMS * 3), i, j, W1, b1, W2, b2, m);

    const float scale = valid ? 1.0f : 0.0f;
    #pragma unroll
    for (int f = 0; f < NF; ++f)
        lds_m[widx][lane * 65 + f] = __float2bfloat16(m[f] * scale);
    lds_i[widx][lane] = i;
    lds_j[widx][lane] = j;
    __syncthreads();

    const float* xb = x + bc * (N_ATOMS * NF);
    float* ob = out + bc * (N_ATOMS * NF);
    int cur_i = lds_i[widx][0];
    float acc_i = 0.0f;
    for (int ee = 0; ee < 64; ++ee) {
        int ie = lds_i[widx][ee];
        int je = lds_j[widx][ee];
        float mv = __bfloat162float(lds_m[widx][ee * 65 + lane]);
        float xi = xb[ie * NF + lane];
        float xj = xb[je * NF + lane];
        atomicAdd(&ob[je * NF + lane], mv * xi);
        if (ie != cur_i) {
            atomicAdd(&ob[cur_i * NF + lane], acc_i);
            acc_i = 0.0f;
            cur_i = ie;
        }
        acc_i = fmaf(mv, xj, acc_i);
    }
    atomicAdd(&ob[cur_i * NF + lane], acc_i);
}

extern "C" void kernel_launch(void* const* d_in, const int* in_sizes, int n_in,
                              void* d_out, int out_size, void* d_ws, size_t ws_size,
                              hipStream_t stream) {
    const float* x   = (const float*)d_in[0];
    const float* xyz = (const float*)d_in[1];
    const int*   seg = (const int*)d_in[2];
    const float* W1  = (const float*)d_in[3];
    const float* b1  = (const float*)d_in[4];
    const float* W2  = (const float*)d_in[5];
    const float* b2  = (const float*)d_in[6];
    float* out = (float*)d_out;

    const int P = in_sizes[2] / 4;              // 129795 edges
    const int n_tiles = (P + 63) / 64;          // 2029
    const size_t need_ws = (size_t)NB * P * NF * sizeof(uint16_t);  // ~126.8 MiB

    if (ws_size >= need_ws && out_size >= NT * NF) {
        uint16_t* mws = (uint16_t*)d_ws;        // bf16 m rows [b][e][f]
        float* tab = out;                        // 1 MB m(wr) table borrows d_out;
                                                 // pass2 overwrites every element after

        hipLaunchKernelGGL(build_tab, dim3((NT * 8) / 256), dim3(256), 0, stream,
                           W1, b1, W2, b2, tab);

        const int total_waves = NB * n_tiles;    // 16232 (exactly divisible by 4)
        hipLaunchKernelGGL(pass1_tab, dim3(total_waves / 4), dim3(256), 0, stream,
                           xyz, seg, tab, mws, P, n_tiles);

        hipLaunchKernelGGL(pass2_agg_kernel, dim3((NB * N_ATOMS) / 4), dim3(256), 0, stream,
                           x, mws, out, P);
    } else {
        const int n = out_size;
        hipLaunchKernelGGL(init_out_kernel, dim3((n + 255) / 256), dim3(256), 0, stream,
                           x, out, n);
        const int total_waves = NB * n_tiles;
        const int blocks = (total_waves + 3) / 4;
        hipLaunchKernelGGL(writhe_msg_atomic_kernel, dim3(blocks), dim3(256), 0, stream,
                           x, xyz, seg, W1, b1, W2, b2, out, P, n_tiles);
    }
}